// Round 1
// baseline (92.094 us; speedup 1.0000x reference)
//
#include <hip/hip_runtime.h>

#define LOG2E 1.4426950408889634f

__device__ __forceinline__ float fast_exp2(float x) {
#if __has_builtin(__builtin_amdgcn_exp2f)
    return __builtin_amdgcn_exp2f(x);
#else
    return exp2f(x);
#endif
}

// One block per (b,h) row. 256 threads = one per w position.
// Stage k0,k1,v0,v1 per u in LDS (float4, broadcast-read by all lanes).
// Single-pass softmax using a per-row Cauchy-Schwarz upper bound as the shift:
//   |q·k| <= max|q| * max|k|  ->  no overflow; underflow provably benign
//   (largest per-w term >= exp(-mb), mb ~ O(30) worst case >> log(FLT_MIN)).
__global__ __launch_bounds__(256, 4) void csa_kernel(
    const float* __restrict__ x1, const float* __restrict__ x2,
    const float* __restrict__ wq, const float* __restrict__ bq,
    const float* __restrict__ wk, const float* __restrict__ bk,
    const float* __restrict__ wv, const float* __restrict__ bv,
    float* __restrict__ out1, float* __restrict__ out2)
{
    constexpr int W = 256;
    __shared__ float4 kv[W];
    __shared__ float redq[4], redk[4];

    const int tid = threadIdx.x;
    const long base = (long)blockIdx.x * W;

    const float xv1 = x1[base + tid];
    const float xv2 = x2[base + tid];

    // weights: uniform pointers + constant indices -> scalar loads
    const float wq00 = wq[0], wq01 = wq[1], wq10 = wq[2], wq11 = wq[3];
    const float wk00 = wk[0], wk01 = wk[1], wk10 = wk[2], wk11 = wk[3];
    const float wv00 = wv[0], wv01 = wv[1], wv10 = wv[2], wv11 = wv[3];
    const float bq0 = bq[0], bq1 = bq[1];
    const float bk0 = bk[0], bk1 = bk[1];
    const float bv0 = bv[0], bv1 = bv[1];

    // per-position projections (w[o][i]: out_o = w[o][0]*x1 + w[o][1]*x2 + b[o])
    const float q0 = fmaf(wq00, xv1, fmaf(wq01, xv2, bq0));
    const float q1 = fmaf(wq10, xv1, fmaf(wq11, xv2, bq1));
    const float k0 = fmaf(wk00, xv1, fmaf(wk01, xv2, bk0));
    const float k1 = fmaf(wk10, xv1, fmaf(wk11, xv2, bk1));
    const float v0 = fmaf(wv00, xv1, fmaf(wv01, xv2, bv0));
    const float v1 = fmaf(wv10, xv1, fmaf(wv11, xv2, bv1));

    kv[tid] = make_float4(k0, k1, v0, v1);

    // block-reduce max|q|^2 and max|k|^2 (wave shuffle + tiny LDS)
    float q2 = fmaf(q0, q0, q1 * q1);
    float k2 = fmaf(k0, k0, k1 * k1);
#pragma unroll
    for (int off = 32; off >= 1; off >>= 1) {
        q2 = fmaxf(q2, __shfl_xor(q2, off, 64));
        k2 = fmaxf(k2, __shfl_xor(k2, off, 64));
    }
    const int wave = tid >> 6;
    if ((tid & 63) == 0) { redq[wave] = q2; redk[wave] = k2; }
    __syncthreads();

    const float mq2 = fmaxf(fmaxf(redq[0], redq[1]), fmaxf(redq[2], redq[3]));
    const float mk2 = fmaxf(fmaxf(redk[0], redk[1]), fmaxf(redk[2], redk[3]));
    const float mb = sqrtf(mq2 * mk2);   // >= max_{w,u} |q·k|

    const float ql0 = q0 * LOG2E;
    const float ql1 = q1 * LOG2E;
    const float csh = -mb * LOG2E;

    float sum = 0.f, o0 = 0.f, o1 = 0.f;
#pragma unroll 8
    for (int u = 0; u < W; ++u) {
        const float4 t = kv[u];                              // broadcast b128
        const float s = fmaf(ql0, t.x, fmaf(ql1, t.y, csh)); // (q·k - mb)*log2e
        const float e = fast_exp2(s);
        sum += e;
        o0 = fmaf(e, t.z, o0);
        o1 = fmaf(e, t.w, o1);
    }

    const float inv = 1.0f / sum;
    out1[base + tid] = fmaf(o0, inv, xv1);
    out2[base + tid] = fmaf(o1, inv, xv2);
}

extern "C" void kernel_launch(void* const* d_in, const int* in_sizes, int n_in,
                              void* d_out, int out_size, void* d_ws, size_t ws_size,
                              hipStream_t stream) {
    const float* x1 = (const float*)d_in[0];
    const float* x2 = (const float*)d_in[1];
    const float* wq = (const float*)d_in[2];
    const float* bq = (const float*)d_in[3];
    const float* wk = (const float*)d_in[4];
    const float* bk = (const float*)d_in[5];
    const float* wv = (const float*)d_in[6];
    const float* bv = (const float*)d_in[7];

    float* out = (float*)d_out;
    const int BHW = in_sizes[0];          // 4*512*256 = 524288
    const int rows = BHW / 256;           // B*H = 2048

    csa_kernel<<<rows, 256, 0, stream>>>(x1, x2, wq, bq, wk, bk, wv, bv,
                                         out, out + BHW);
}

// Round 2
// 91.630 us; speedup vs baseline: 1.0051x; 1.0051x over previous
//
#include <hip/hip_runtime.h>

typedef float v2f __attribute__((ext_vector_type(2)));

#define LOG2E 1.4426950408889634f

__device__ __forceinline__ float fast_exp2(float x) {
#if __has_builtin(__builtin_amdgcn_exp2f)
    return __builtin_amdgcn_exp2f(x);
#else
    return exp2f(x);
#endif
}

__device__ __forceinline__ v2f pk_fma(v2f a, v2f b, v2f c) {
    return __builtin_elementwise_fma(a, b, c);
}

// One WAVE per (b,h) row: lane l owns w = 4l..4l+3 (contiguous -> float4
// global I/O). kv staged per-wave in LDS as u-PAIR-packed float4 so the
// inner math maps onto v_pk_fma_f32 (full-rate packed fp32 on gfx950).
// Each broadcast ds_read_b128 pair now feeds 4w x 2u x 64 lanes = 512
// score entries (vs 64 before) -> LDS-pipe insts cut 4x.
// Single-pass softmax via per-row Cauchy-Schwarz bound (see R0 analysis).
__global__ __launch_bounds__(256, 2) void csa_kernel(
    const float* __restrict__ x1, const float* __restrict__ x2,
    const float* __restrict__ wq, const float* __restrict__ bq,
    const float* __restrict__ wk, const float* __restrict__ bk,
    const float* __restrict__ wv, const float* __restrict__ bv,
    float* __restrict__ out1, float* __restrict__ out2)
{
    constexpr int W = 256;
    __shared__ float4 sK[4][W / 2];   // per wave: (k0[u0],k0[u1],k1[u0],k1[u1])
    __shared__ float4 sV[4][W / 2];   // per wave: (v0[u0],v0[u1],v1[u0],v1[u1])

    const int tid = threadIdx.x;
    const int wv_id = tid >> 6;
    const int l = tid & 63;
    const long row = (long)blockIdx.x * 4 + wv_id;
    const long base = row * W;

    // coalesced float4 loads: lane l covers w = 4l..4l+3
    const float4 xa = *(const float4*)(x1 + base + 4 * l);
    const float4 xb = *(const float4*)(x2 + base + 4 * l);
    const float X1[4] = {xa.x, xa.y, xa.z, xa.w};
    const float X2[4] = {xb.x, xb.y, xb.z, xb.w};

    // weights -> scalar regs
    const float wq00 = wq[0], wq01 = wq[1], wq10 = wq[2], wq11 = wq[3];
    const float wk00 = wk[0], wk01 = wk[1], wk10 = wk[2], wk11 = wk[3];
    const float wv00 = wv[0], wv01 = wv[1], wv10 = wv[2], wv11 = wv[3];
    const float bq0 = bq[0], bq1 = bq[1];
    const float bk0 = bk[0], bk1 = bk[1];
    const float bv0 = bv[0], bv1 = bv[1];

    float q0[4], q1[4], k0[4], k1[4], v0[4], v1[4];
#pragma unroll
    for (int j = 0; j < 4; ++j) {
        q0[j] = fmaf(wq00, X1[j], fmaf(wq01, X2[j], bq0));
        q1[j] = fmaf(wq10, X1[j], fmaf(wq11, X2[j], bq1));
        k0[j] = fmaf(wk00, X1[j], fmaf(wk01, X2[j], bk0));
        k1[j] = fmaf(wk10, X1[j], fmaf(wk11, X2[j], bk1));
        v0[j] = fmaf(wv00, X1[j], fmaf(wv01, X2[j], bv0));
        v1[j] = fmaf(wv10, X1[j], fmaf(wv11, X2[j], bv1));
    }

    sK[wv_id][2 * l + 0] = make_float4(k0[0], k0[1], k1[0], k1[1]);
    sK[wv_id][2 * l + 1] = make_float4(k0[2], k0[3], k1[2], k1[3]);
    sV[wv_id][2 * l + 0] = make_float4(v0[0], v0[1], v1[0], v1[1]);
    sV[wv_id][2 * l + 1] = make_float4(v0[2], v0[3], v1[2], v1[3]);

    // wave-level max|q|^2, max|k|^2 (row is wave-private; no cross-wave sync)
    float q2 = 0.f, k2 = 0.f;
#pragma unroll
    for (int j = 0; j < 4; ++j) {
        q2 = fmaxf(q2, fmaf(q0[j], q0[j], q1[j] * q1[j]));
        k2 = fmaxf(k2, fmaf(k0[j], k0[j], k1[j] * k1[j]));
    }
#pragma unroll
    for (int off = 32; off >= 1; off >>= 1) {
        q2 = fmaxf(q2, __shfl_xor(q2, off, 64));
        k2 = fmaxf(k2, __shfl_xor(k2, off, 64));
    }
    const float mb = sqrtf(q2 * k2);      // >= max_{w,u} |q·k|
    const float csh = -mb * LOG2E;

    __syncthreads();   // orders LDS write->read (also covers same-wave RAW)

    const v2f cshv = {csh, csh};
    v2f ql0[4], ql1[4], sum[4], o0[4], o1[4];
#pragma unroll
    for (int j = 0; j < 4; ++j) {
        const float a0 = q0[j] * LOG2E, a1 = q1[j] * LOG2E;
        ql0[j] = (v2f){a0, a0};
        ql1[j] = (v2f){a1, a1};
        sum[j] = (v2f){0.f, 0.f};
        o0[j]  = (v2f){0.f, 0.f};
        o1[j]  = (v2f){0.f, 0.f};
    }

#pragma unroll 4
    for (int up = 0; up < W / 2; ++up) {
        const float4 K = sK[wv_id][up];   // broadcast b128 (no conflicts)
        const float4 V = sV[wv_id][up];
        const v2f kx = {K.x, K.y};        // k0 at u0,u1
        const v2f kz = {K.z, K.w};        // k1 at u0,u1
        const v2f vx = {V.x, V.y};        // v0 at u0,u1
        const v2f vz = {V.z, V.w};        // v1 at u0,u1
#pragma unroll
        for (int j = 0; j < 4; ++j) {
            v2f s = pk_fma(ql0[j], kx, pk_fma(ql1[j], kz, cshv));
            v2f e;
            e.x = fast_exp2(s.x);
            e.y = fast_exp2(s.y);
            sum[j] += e;                  // v_pk_add_f32
            o0[j] = pk_fma(e, vx, o0[j]);
            o1[j] = pk_fma(e, vz, o1[j]);
        }
    }

    float r1[4], r2[4];
#pragma unroll
    for (int j = 0; j < 4; ++j) {
        const float s = sum[j].x + sum[j].y;
        const float inv = 1.0f / s;
        r1[j] = fmaf(o0[j].x + o0[j].y, inv, X1[j]);
        r2[j] = fmaf(o1[j].x + o1[j].y, inv, X2[j]);
    }
    *(float4*)(out1 + base + 4 * l) = make_float4(r1[0], r1[1], r1[2], r1[3]);
    *(float4*)(out2 + base + 4 * l) = make_float4(r2[0], r2[1], r2[2], r2[3]);
}

extern "C" void kernel_launch(void* const* d_in, const int* in_sizes, int n_in,
                              void* d_out, int out_size, void* d_ws, size_t ws_size,
                              hipStream_t stream) {
    const float* x1 = (const float*)d_in[0];
    const float* x2 = (const float*)d_in[1];
    const float* wq = (const float*)d_in[2];
    const float* bq = (const float*)d_in[3];
    const float* wk = (const float*)d_in[4];
    const float* bk = (const float*)d_in[5];
    const float* wv = (const float*)d_in[6];
    const float* bv = (const float*)d_in[7];

    float* out = (float*)d_out;
    const int BHW = in_sizes[0];            // 4*512*256 = 524288
    const int rows = BHW / 256;             // B*H = 2048

    csa_kernel<<<rows / 4, 256, 0, stream>>>(x1, x2, wq, bq, wk, bk, wv, bv,
                                             out, out + BHW);
}

// Round 3
// 89.817 us; speedup vs baseline: 1.0254x; 1.0202x over previous
//
#include <hip/hip_runtime.h>

typedef float v2f __attribute__((ext_vector_type(2)));

#define LOG2E 1.4426950408889634f

__device__ __forceinline__ float fast_exp2(float x) {
#if __has_builtin(__builtin_amdgcn_exp2f)
    return __builtin_amdgcn_exp2f(x);
#else
    return exp2f(x);
#endif
}

__device__ __forceinline__ v2f pk_fma(v2f a, v2f b, v2f c) {
    return __builtin_elementwise_fma(a, b, c);
}

// v3: one BLOCK (4 waves) per (b,h) row; the u-range is split 4 ways across
// the waves (32 u-pair iters each, vs 128 in v2). Grid 2048 blocks ->
// 4 blocks/CU, launch_bounds(256,4) -> 16 waves/CU: 2x the TLP of v2 with
// 4x shorter dependency chains. This discriminates "kernel is stall-bound
// at ~48us" (B) from "timed window is dominated by harness fills" (A).
//
// Every wave loads the whole row (float4, L1-cached after wave 0) and
// computes q + the Cauchy-Schwarz softmax shift redundantly (no cross-wave
// reduction needed). Wave 0 stages pair-packed k/v in LDS. Partial
// (sum, o0, o1) per w are combined through a small LDS buffer; wave 0
// writes the output.
__global__ __launch_bounds__(256, 4) void csa_kernel(
    const float* __restrict__ x1, const float* __restrict__ x2,
    const float* __restrict__ wq, const float* __restrict__ bq,
    const float* __restrict__ wk, const float* __restrict__ bk,
    const float* __restrict__ wv, const float* __restrict__ bv,
    float* __restrict__ out1, float* __restrict__ out2)
{
    constexpr int W = 256;
    __shared__ float4 sK[W / 2];          // (k0[u0],k0[u1],k1[u0],k1[u1])
    __shared__ float4 sV[W / 2];          // (v0[u0],v0[u1],v1[u0],v1[u1])
    __shared__ float4 pS[4][64];          // partial sum  per wave/lane (j=0..3)
    __shared__ float4 pA[4][64];          // partial o0
    __shared__ float4 pB[4][64];          // partial o1

    const int tid = threadIdx.x;
    const int wid = tid >> 6;
    const int l = tid & 63;
    const long base = (long)blockIdx.x * W;

    // every wave loads the full row: lane l covers w = 4l..4l+3
    const float4 xa = *(const float4*)(x1 + base + 4 * l);
    const float4 xb = *(const float4*)(x2 + base + 4 * l);
    const float X1[4] = {xa.x, xa.y, xa.z, xa.w};
    const float X2[4] = {xb.x, xb.y, xb.z, xb.w};

    const float wq00 = wq[0], wq01 = wq[1], wq10 = wq[2], wq11 = wq[3];
    const float wk00 = wk[0], wk01 = wk[1], wk10 = wk[2], wk11 = wk[3];
    const float bq0 = bq[0], bq1 = bq[1];
    const float bk0 = bk[0], bk1 = bk[1];

    float q0[4], q1[4], k0[4], k1[4];
#pragma unroll
    for (int j = 0; j < 4; ++j) {
        q0[j] = fmaf(wq00, X1[j], fmaf(wq01, X2[j], bq0));
        q1[j] = fmaf(wq10, X1[j], fmaf(wq11, X2[j], bq1));
        k0[j] = fmaf(wk00, X1[j], fmaf(wk01, X2[j], bk0));
        k1[j] = fmaf(wk10, X1[j], fmaf(wk11, X2[j], bk1));
    }

    if (wid == 0) {   // wave-uniform branch: wave 0 stages k/v for the block
        const float wv00 = wv[0], wv01 = wv[1], wv10 = wv[2], wv11 = wv[3];
        const float bv0 = bv[0], bv1 = bv[1];
        float v0[4], v1[4];
#pragma unroll
        for (int j = 0; j < 4; ++j) {
            v0[j] = fmaf(wv00, X1[j], fmaf(wv01, X2[j], bv0));
            v1[j] = fmaf(wv10, X1[j], fmaf(wv11, X2[j], bv1));
        }
        sK[2 * l + 0] = make_float4(k0[0], k0[1], k1[0], k1[1]);
        sK[2 * l + 1] = make_float4(k0[2], k0[3], k1[2], k1[3]);
        sV[2 * l + 0] = make_float4(v0[0], v0[1], v1[0], v1[1]);
        sV[2 * l + 1] = make_float4(v0[2], v0[3], v1[2], v1[3]);
    }

    // per-wave (== per-row, redundant across waves) Cauchy-Schwarz bound
    float q2 = 0.f, k2 = 0.f;
#pragma unroll
    for (int j = 0; j < 4; ++j) {
        q2 = fmaxf(q2, fmaf(q0[j], q0[j], q1[j] * q1[j]));
        k2 = fmaxf(k2, fmaf(k0[j], k0[j], k1[j] * k1[j]));
    }
#pragma unroll
    for (int off = 32; off >= 1; off >>= 1) {
        q2 = fmaxf(q2, __shfl_xor(q2, off, 64));
        k2 = fmaxf(k2, __shfl_xor(k2, off, 64));
    }
    const float mb = sqrtf(q2 * k2);      // >= max_{w,u} |q·k|
    const float csh = -mb * LOG2E;
    const v2f cshv = {csh, csh};

    v2f ql0[4], ql1[4], sum[4], o0[4], o1[4];
#pragma unroll
    for (int j = 0; j < 4; ++j) {
        const float a0 = q0[j] * LOG2E, a1 = q1[j] * LOG2E;
        ql0[j] = (v2f){a0, a0};
        ql1[j] = (v2f){a1, a1};
        sum[j] = (v2f){0.f, 0.f};
        o0[j]  = (v2f){0.f, 0.f};
        o1[j]  = (v2f){0.f, 0.f};
    }

    __syncthreads();

    // this wave's u-chunk: 32 u-pairs
    const int up0 = 32 * wid;
#pragma unroll 4
    for (int up = up0; up < up0 + 32; ++up) {
        const float4 K = sK[up];          // broadcast b128, conflict-free
        const float4 V = sV[up];
        const v2f kx = {K.x, K.y};
        const v2f kz = {K.z, K.w};
        const v2f vx = {V.x, V.y};
        const v2f vz = {V.z, V.w};
#pragma unroll
        for (int j = 0; j < 4; ++j) {
            v2f s = pk_fma(ql0[j], kx, pk_fma(ql1[j], kz, cshv));
            v2f e;
            e.x = fast_exp2(s.x);
            e.y = fast_exp2(s.y);
            sum[j] += e;
            o0[j] = pk_fma(e, vx, o0[j]);
            o1[j] = pk_fma(e, vz, o1[j]);
        }
    }

    // publish partials (uniform shift -> partial sums combine additively)
    pS[wid][l] = make_float4(sum[0].x + sum[0].y, sum[1].x + sum[1].y,
                             sum[2].x + sum[2].y, sum[3].x + sum[3].y);
    pA[wid][l] = make_float4(o0[0].x + o0[0].y, o0[1].x + o0[1].y,
                             o0[2].x + o0[2].y, o0[3].x + o0[3].y);
    pB[wid][l] = make_float4(o1[0].x + o1[0].y, o1[1].x + o1[1].y,
                             o1[2].x + o1[2].y, o1[3].x + o1[3].y);

    __syncthreads();

    if (wid == 0) {
        const float4 s0 = pS[0][l], s1 = pS[1][l], s2 = pS[2][l], s3 = pS[3][l];
        const float4 a0 = pA[0][l], a1 = pA[1][l], a2 = pA[2][l], a3 = pA[3][l];
        const float4 b0 = pB[0][l], b1 = pB[1][l], b2 = pB[2][l], b3 = pB[3][l];
        const float S[4] = {s0.x + s1.x + s2.x + s3.x, s0.y + s1.y + s2.y + s3.y,
                            s0.z + s1.z + s2.z + s3.z, s0.w + s1.w + s2.w + s3.w};
        const float A[4] = {a0.x + a1.x + a2.x + a3.x, a0.y + a1.y + a2.y + a3.y,
                            a0.z + a1.z + a2.z + a3.z, a0.w + a1.w + a2.w + a3.w};
        const float Bv[4] = {b0.x + b1.x + b2.x + b3.x, b0.y + b1.y + b2.y + b3.y,
                             b0.z + b1.z + b2.z + b3.z, b0.w + b1.w + b2.w + b3.w};
        float r1[4], r2[4];
#pragma unroll
        for (int j = 0; j < 4; ++j) {
            const float inv = 1.0f / S[j];
            r1[j] = fmaf(A[j], inv, X1[j]);
            r2[j] = fmaf(Bv[j], inv, X2[j]);
        }
        *(float4*)(out1 + base + 4 * l) = make_float4(r1[0], r1[1], r1[2], r1[3]);
        *(float4*)(out2 + base + 4 * l) = make_float4(r2[0], r2[1], r2[2], r2[3]);
    }
}

extern "C" void kernel_launch(void* const* d_in, const int* in_sizes, int n_in,
                              void* d_out, int out_size, void* d_ws, size_t ws_size,
                              hipStream_t stream) {
    const float* x1 = (const float*)d_in[0];
    const float* x2 = (const float*)d_in[1];
    const float* wq = (const float*)d_in[2];
    const float* bq = (const float*)d_in[3];
    const float* wk = (const float*)d_in[4];
    const float* bk = (const float*)d_in[5];
    const float* wv = (const float*)d_in[6];
    const float* bv = (const float*)d_in[7];

    float* out = (float*)d_out;
    const int BHW = in_sizes[0];            // 4*512*256 = 524288
    const int rows = BHW / 256;             // B*H = 2048

    csa_kernel<<<rows, 256, 0, stream>>>(x1, x2, wq, bq, wk, bk, wv, bv,
                                         out, out + BHW);
}